// Round 9
// baseline (7357.977 us; speedup 1.0000x reference)
//
#include <hip/hip_runtime.h>
#include <hip/hip_cooperative_groups.h>

#define HID 2048
#define BAT 512
#define SEQ 128
#define NCLS 10

typedef __attribute__((ext_vector_type(4))) float f32x4;
typedef __attribute__((ext_vector_type(8))) short s16x8;
typedef __attribute__((ext_vector_type(4))) unsigned short u16x4;

__device__ __forceinline__ float bf2f(unsigned short u) {
  union { unsigned int i; float f; } v;
  v.i = ((unsigned int)u) << 16;
  return v.f;
}
__device__ __forceinline__ unsigned short f2bf(float f) {
  union { float f; unsigned int i; } v;
  v.f = f;
  unsigned int u = v.i;
  return (unsigned short)((u + 0x7fffu + ((u >> 16) & 1u)) >> 16);
}

// fp32 -> bf16, 4 elems/thread
__global__ __launch_bounds__(256) void cvt_kernel(const float* __restrict__ src,
                                                  unsigned short* __restrict__ dst,
                                                  int n) {
  int i = (blockIdx.x * 256 + threadIdx.x) * 4;
  if (i + 3 < n) {
    f32x4 v = *(const f32x4*)(src + i);
    u16x4 o;
    o.x = f2bf(v.x);
    o.y = f2bf(v.y);
    o.z = f2bf(v.z);
    o.w = f2bf(v.w);
    *(u16x4*)(dst + i) = o;
  }
}

// x[BAT][SEQ] -> xT[SEQ][BAT]
__global__ __launch_bounds__(256) void xpose_kernel(const float* __restrict__ x,
                                                    float* __restrict__ xT) {
  const int t = blockIdx.x;
  for (int b = threadIdx.x; b < BAT; b += 256)
    xT[t * BAT + b] = x[b * SEQ + t];
}

__device__ __forceinline__ void gload16(const void* g, void* l) {
  __builtin_amdgcn_global_load_lds(
      (const __attribute__((address_space(1))) unsigned int*)g,
      (__attribute__((address_space(3))) unsigned int*)l, 16, 0, 0);
}

// Persistent RNN, W-STATIONARY IN LDS.
// 256 blocks = (mp 0..63 m-panels of 32 rows) x (g 0..3 batch groups of 128).
// Block's W chunk (32 x 2048 bf16 = 128 KiB) is loaded into LDS ONCE and reused
// for all 128 steps -> W HBM traffic 1.05 GB -> 8 MB one-time (round-8 counters
// showed the per-step W HBM refetch was 93% of runtime).
// B (h) fragments are loaded global->VGPR directly (default cache policy, L2-
// served), 4-buffer depth-2 software prefetch. No LDS staging for B at all.
// Cross-step coherence: round-5-proven __threadfence / barrier / __threadfence
// (the acquire-invalidate is now cheap: W lives in LDS, immune to it).
// Group barrier: relaxed agent-scope atomic counter per g, target 64*(t+1).
__global__ __launch_bounds__(256) void rnn_kernel(
    const unsigned short* __restrict__ W,
    unsigned short* __restrict__ h0,
    unsigned short* __restrict__ h1,
    const float* __restrict__ whx,   // [HID]
    const float* __restrict__ bh,    // [HID]
    const float* __restrict__ xT,    // [SEQ][BAT]
    unsigned int* __restrict__ cnt) {
  __shared__ unsigned short ldsW[32 * HID];  // 128 KiB, resident all 128 steps

  const int tid = threadIdx.x;
  const int wave = tid >> 6;
  const int lane = tid & 63;
  const int id = blockIdx.x;
  const int mp = id >> 2;   // m-panel: rows [32*mp, 32*mp+32)
  const int g = id & 3;     // batch group: cols [128*g, 128*g+128)
  const int n0 = g * 128;
  const int fl = lane & 15;
  const int hi = lane >> 4;

  // ---- stage W panel into LDS once (linear dest; involution-swizzled source
  //      chunk so the swizzled fragment reads below are bank-conflict-free)
  {
    const unsigned short* wp0 = W + (size_t)mp * 32 * HID;
    for (int i = 0; i < 32; ++i) {
      gload16(wp0 + (size_t)i * HID + ((tid ^ (i & 7)) * 8),
              ldsW + i * HID + wave * 512);
    }
    asm volatile("s_waitcnt vmcnt(0)" ::: "memory");
    __syncthreads();
  }

  // A-fragment LDS offsets (elem; kk-invariant part). row stride 4096 B; the
  // chunk^(row&7) swizzle spreads the 16 fl-rows across 8 bank-quads (same
  // pattern as rounds 4-8: measured 0 bank conflicts).
  int oA[2][2];
#pragma unroll
  for (int mf = 0; mf < 2; ++mf)
#pragma unroll
    for (int ks = 0; ks < 2; ++ks) {
      const int row = mf * 16 + fl;
      oA[mf][ks] = row * HID + (((ks * 4 + hi) ^ (row & 7)) * 8);
    }

  // B global base offsets (elem). Waves split n: wave owns cols [32*wave, +32).
  size_t oB[2][2];
#pragma unroll
  for (int nf = 0; nf < 2; ++nf)
#pragma unroll
    for (int ks = 0; ks < 2; ++ks)
      oB[nf][ks] =
          (size_t)(n0 + wave * 32 + nf * 16 + fl) * HID + ks * 32 + hi * 8;

  // t-invariant epilogue constants
  f32x4 wxv[2], bvv[2];
#pragma unroll
  for (int mf = 0; mf < 2; ++mf) {
    wxv[mf] = *(const f32x4*)&whx[mp * 32 + mf * 16 + hi * 4];
    bvv[mf] = *(const f32x4*)&bh[mp * 32 + mf * 16 + hi * 4];
  }

// load B fragments for K-step kk into named buffer X (b[nf][ks])
#define LB(X, kk)                                        \
  do {                                                   \
    X##00 = *(const s16x8*)&hp[oB[0][0] + (kk) * 64];    \
    X##01 = *(const s16x8*)&hp[oB[0][1] + (kk) * 64];    \
    X##10 = *(const s16x8*)&hp[oB[1][0] + (kk) * 64];    \
    X##11 = *(const s16x8*)&hp[oB[1][1] + (kk) * 64];    \
  } while (0)

// acc[mf][nf] += a[mf][ks] * b[nf][ks], ks = 0,1
#define MF(X, kk)                                                                      \
  do {                                                                                 \
    const int ko = (kk) * 64;                                                          \
    s16x8 a00 = *(const s16x8*)&ldsW[oA[0][0] + ko];                                   \
    s16x8 a10 = *(const s16x8*)&ldsW[oA[1][0] + ko];                                   \
    acc[0][0] = __builtin_amdgcn_mfma_f32_16x16x32_bf16(a00, X##00, acc[0][0], 0,0,0); \
    acc[0][1] = __builtin_amdgcn_mfma_f32_16x16x32_bf16(a00, X##10, acc[0][1], 0,0,0); \
    acc[1][0] = __builtin_amdgcn_mfma_f32_16x16x32_bf16(a10, X##00, acc[1][0], 0,0,0); \
    acc[1][1] = __builtin_amdgcn_mfma_f32_16x16x32_bf16(a10, X##10, acc[1][1], 0,0,0); \
    s16x8 a01 = *(const s16x8*)&ldsW[oA[0][1] + ko];                                   \
    s16x8 a11 = *(const s16x8*)&ldsW[oA[1][1] + ko];                                   \
    acc[0][0] = __builtin_amdgcn_mfma_f32_16x16x32_bf16(a01, X##01, acc[0][0], 0,0,0); \
    acc[0][1] = __builtin_amdgcn_mfma_f32_16x16x32_bf16(a01, X##11, acc[0][1], 0,0,0); \
    acc[1][0] = __builtin_amdgcn_mfma_f32_16x16x32_bf16(a11, X##01, acc[1][0], 0,0,0); \
    acc[1][1] = __builtin_amdgcn_mfma_f32_16x16x32_bf16(a11, X##11, acc[1][1], 0,0,0); \
  } while (0)

  for (int t = 0; t < SEQ; ++t) {
    const unsigned short* hp = (t & 1) ? h1 : h0;
    unsigned short* hq = (t & 1) ? h0 : h1;

    f32x4 acc[2][2] = {};
    s16x8 BA00, BA01, BA10, BA11;
    s16x8 BB00, BB01, BB10, BB11;
    s16x8 BC00, BC01, BC10, BC11;
    s16x8 BD00, BD01, BD10, BD11;

    // depth-2 software pipeline over 32 K-steps of 64
    LB(BA, 0);
    LB(BB, 1);
#pragma unroll 1
    for (int kb = 0; kb < 28; kb += 4) {
      LB(BC, kb + 2); MF(BA, kb + 0);
      LB(BD, kb + 3); MF(BB, kb + 1);
      LB(BA, kb + 4); MF(BC, kb + 2);
      LB(BB, kb + 5); MF(BD, kb + 3);
    }
    LB(BC, 30); MF(BA, 28);
    LB(BD, 31); MF(BB, 29);
    MF(BC, 30);
    MF(BD, 31);

    // epilogue: C/D layout col(n)=lane&15, row(m)=hi*4+j  [m89/m91-verified]
#pragma unroll
    for (int mf = 0; mf < 2; ++mf) {
      const int mrow = mp * 32 + mf * 16 + hi * 4;
#pragma unroll
      for (int nf = 0; nf < 2; ++nf) {
        const int ncol = n0 + wave * 32 + nf * 16 + fl;
        const float xv = xT[t * BAT + ncol];
        u16x4 o;
#pragma unroll
        for (int j = 0; j < 4; ++j) {
          float z = acc[mf][nf][j] + wxv[mf][j] * xv + bvv[mf][j];
          o[j] = f2bf(tanhf(z));
        }
        *(u16x4*)&hq[(size_t)ncol * HID + mrow] = o;  // plain (cached) store
      }
    }

    if (t != SEQ - 1) {
      __threadfence();   // release: drain + write back (round-5-proven pattern)
      __syncthreads();
      if (tid == 0) {
        __hip_atomic_fetch_add(&cnt[g * 16], 1u, __ATOMIC_RELAXED,
                               __HIP_MEMORY_SCOPE_AGENT);
        const unsigned int target = 64u * (unsigned)(t + 1);
        while (__hip_atomic_load(&cnt[g * 16], __ATOMIC_RELAXED,
                                 __HIP_MEMORY_SCOPE_AGENT) < target)
          __builtin_amdgcn_s_sleep(1);
      }
      __syncthreads();
      __threadfence();   // acquire: invalidate stale L1/L2 before reading new h
    }
  }
#undef LB
#undef MF
}

// out[b][c] = sum_k wp[c][k] * hT[b][k] + bp[c]
__global__ __launch_bounds__(256) void proj_kernel(const unsigned short* __restrict__ hT,
                                                   const float* __restrict__ wp,
                                                   const float* __restrict__ bp,
                                                   float* __restrict__ out) {
  const int b = blockIdx.x;
  const int wave = threadIdx.x >> 6;
  const int lane = threadIdx.x & 63;
  for (int c = wave; c < NCLS; c += 4) {
    float s = 0.f;
    for (int k = lane * 8; k < HID; k += 512) {
      s16x8 hv = *(const s16x8*)&hT[b * HID + k];
      f32x4 w0 = *(const f32x4*)&wp[c * HID + k];
      f32x4 w1 = *(const f32x4*)&wp[c * HID + k + 4];
      s += w0.x * bf2f((unsigned short)hv[0]) + w0.y * bf2f((unsigned short)hv[1]) +
           w0.z * bf2f((unsigned short)hv[2]) + w0.w * bf2f((unsigned short)hv[3]) +
           w1.x * bf2f((unsigned short)hv[4]) + w1.y * bf2f((unsigned short)hv[5]) +
           w1.z * bf2f((unsigned short)hv[6]) + w1.w * bf2f((unsigned short)hv[7]);
    }
#pragma unroll
    for (int off = 32; off > 0; off >>= 1) s += __shfl_down(s, off);
    if (lane == 0) out[b * NCLS + c] = s + bp[c];
  }
}

extern "C" void kernel_launch(void* const* d_in, const int* in_sizes, int n_in,
                              void* d_out, int out_size, void* d_ws, size_t ws_size,
                              hipStream_t stream) {
  (void)in_sizes; (void)n_in; (void)out_size; (void)ws_size;
  const float* x   = (const float*)d_in[0];  // [BAT][SEQ]
  const float* whx = (const float*)d_in[1];  // [HID][1]
  const float* whh = (const float*)d_in[2];  // [HID][HID]
  const float* bh  = (const float*)d_in[3];  // [HID][1]
  const float* wp  = (const float*)d_in[4];  // [NCLS][HID]
  const float* bp  = (const float*)d_in[5];  // [NCLS][1]
  float* out = (float*)d_out;                // [BAT][NCLS]

  unsigned short* Wb = (unsigned short*)d_ws;          // 8 MiB
  unsigned short* h0 = Wb + (size_t)HID * HID;         // 2 MiB
  unsigned short* h1 = h0 + (size_t)BAT * HID;         // 2 MiB
  float* xT = (float*)(h1 + (size_t)BAT * HID);        // 256 KiB
  unsigned int* cnt = (unsigned int*)(xT + (size_t)SEQ * BAT);  // 4 ctrs, 64B stride

  cvt_kernel<<<dim3((HID * HID) / 1024), 256, 0, stream>>>(whh, Wb, HID * HID);
  xpose_kernel<<<dim3(SEQ), 256, 0, stream>>>(x, xT);
  hipMemsetAsync(h0, 0, (size_t)BAT * HID * sizeof(unsigned short), stream);
  hipMemsetAsync(cnt, 0, 8 * 64, stream);

  const unsigned short* Wb_c = Wb;
  unsigned short* h0_p = h0;
  unsigned short* h1_p = h1;
  const float* whx_p = whx;
  const float* bh_p = bh;
  const float* xT_p = xT;
  unsigned int* cnt_p = cnt;
  void* args[] = {(void*)&Wb_c, (void*)&h0_p, (void*)&h1_p,
                  (void*)&whx_p, (void*)&bh_p, (void*)&xT_p, (void*)&cnt_p};
  hipLaunchCooperativeKernel((const void*)rnn_kernel, dim3(256), dim3(256),
                             args, 0, stream);

  // t=127 (odd) wrote h0
  proj_kernel<<<dim3(BAT), 256, 0, stream>>>(h0, wp, bp, out);
}